// Round 1
// baseline (211.668 us; speedup 1.0000x reference)
//
#include <hip/hip_runtime.h>
#include <hip/hip_bf16.h>

#define B_N 64
#define S_N 2048
#define E_N 512
#define A_N 512

typedef __bf16 bf16x8 __attribute__((ext_vector_type(8)));
typedef float  f32x4  __attribute__((ext_vector_type(4)));

__device__ __forceinline__ unsigned short f2bf(float f) {
  return __builtin_bit_cast(unsigned short, (__bf16)f);
}

// ---------------- K0a: W_enc fp32 [A][E] -> bf16 same layout ----------------
__global__ void k_convw(const float* __restrict__ W, unsigned short* __restrict__ Wbf) {
  const int i = (blockIdx.x * 256 + threadIdx.x) * 4;
  const float4 v = *(const float4*)(W + i);
  ushort4 p;
  p.x = f2bf(v.x); p.y = f2bf(v.y); p.z = f2bf(v.z); p.w = f2bf(v.w);
  *(ushort4*)(Wbf + i) = p;
}

// ---------------- K0b: dec_proj[b][a] = dot(dec_hidden[b], W_dec[a]) --------
__global__ __launch_bounds__(256) void k_decproj(const float* __restrict__ dh,
                                                 const float* __restrict__ Wd,
                                                 float* __restrict__ decp) {
  const int b = blockIdx.x, tid = threadIdx.x;
  __shared__ float h[E_N];
  h[tid] = dh[b * E_N + tid];
  h[tid + 256] = dh[b * E_N + 256 + tid];
  __syncthreads();
  for (int a = tid; a < A_N; a += 256) {
    const float* wr = Wd + (size_t)a * E_N;
    float s = 0.f;
    #pragma unroll 8
    for (int e = 0; e < E_N; e += 4) {
      const float4 w4 = *(const float4*)(wr + e);
      s += w4.x * h[e] + w4.y * h[e + 1] + w4.z * h[e + 2] + w4.w * h[e + 3];
    }
    decp[b * A_N + a] = s;
  }
}

// ---------------- K1: scores = sum_a v[a]*tanh(enc@We^T + decp) -------------
// Block: 64 rows (one b), full A=512 cols; 4 waves x 128 cols; BK=64.
#define A_SZb   (64 * 128)            // A tile: 64 rows x 64 bf16 (128 B rows)
#define B_SZb   (512 * 128)           // B tile: 512 rows x 64 bf16
#define RED_OFF (A_SZb + B_SZb)
#define LDS_TOT (A_SZb + B_SZb + 4 * 64 * 4)

__device__ __forceinline__ int a_off(int r, int cb) {
  return r * 128 + (cb ^ ((r & 7) << 4));
}
__device__ __forceinline__ int b_off(int r, int cb) {
  return A_SZb + r * 128 + (cb ^ ((r & 7) << 4));
}

__global__ __launch_bounds__(256, 2) void k_scores(
    const float* __restrict__ enc, const unsigned short* __restrict__ Wbf,
    const float* __restrict__ decp, const float* __restrict__ vvec,
    float* __restrict__ scores) {
  __shared__ __align__(16) unsigned char lds[LDS_TOT];
  const int tid = threadIdx.x;
  const int lane = tid & 63, wv = tid >> 6, q = lane >> 4, ln = lane & 15;
  const int m0 = blockIdx.x * 64;
  const int b  = m0 >> 11;

  f32x4 acc[4][8] = {};

  for (int ks = 0; ks < 8; ++ks) {
    const int k0 = ks * 64;
    __syncthreads();
    // stage A: 64 rows x 64 fp32 -> bf16 LDS (swizzled)
    {
      const float* Ag = enc + (size_t)m0 * E_N + k0;
      #pragma unroll
      for (int i = 0; i < 4; ++i) {
        const int idx = i * 256 + tid;
        const int row = idx >> 4, c = idx & 15;
        const float4 v4 = *(const float4*)(Ag + (size_t)row * E_N + c * 4);
        ushort4 p;
        p.x = f2bf(v4.x); p.y = f2bf(v4.y); p.z = f2bf(v4.z); p.w = f2bf(v4.w);
        *(ushort4*)(lds + a_off(row, c * 8)) = p;
      }
    }
    // stage B: 512 rows x 64 bf16 from pre-converted W (swizzled)
    {
      const unsigned short* Wg = Wbf + k0;
      #pragma unroll
      for (int i = 0; i < 16; ++i) {
        const int idx = i * 256 + tid;
        const int row = idx >> 3, c = idx & 7;
        const uint4 v4 = *(const uint4*)(Wg + (size_t)row * A_N + c * 8);
        *(uint4*)(lds + b_off(row, c * 16)) = v4;
      }
    }
    __syncthreads();
    #pragma unroll
    for (int kt = 0; kt < 2; ++kt) {
      bf16x8 af[4], bfr[8];
      #pragma unroll
      for (int mt = 0; mt < 4; ++mt)
        af[mt] = *(const bf16x8*)(lds + a_off(mt * 16 + ln, kt * 64 + q * 16));
      #pragma unroll
      for (int nt = 0; nt < 8; ++nt)
        bfr[nt] = *(const bf16x8*)(lds + b_off(wv * 128 + nt * 16 + ln, kt * 64 + q * 16));
      #pragma unroll
      for (int mt = 0; mt < 4; ++mt) {
        #pragma unroll
        for (int nt = 0; nt < 8; ++nt)
          acc[mt][nt] = __builtin_amdgcn_mfma_f32_16x16x32_bf16(af[mt], bfr[nt], acc[mt][nt], 0, 0, 0);
      }
    }
  }

  // epilogue: tanh(x + decp) * v, reduce over a
  float vv[8], dp[8];
  #pragma unroll
  for (int nt = 0; nt < 8; ++nt) {
    const int a = wv * 128 + nt * 16 + ln;
    vv[nt] = vvec[a];
    dp[nt] = decp[b * A_N + a];
  }
  float part[4][4] = {};
  #pragma unroll
  for (int mt = 0; mt < 4; ++mt) {
    #pragma unroll
    for (int nt = 0; nt < 8; ++nt) {
      #pragma unroll
      for (int r = 0; r < 4; ++r) {
        float x = acc[mt][nt][r] + dp[nt];
        x = fminf(9.f, fmaxf(-9.f, x));
        const float ex = __expf(2.f * x);
        part[mt][r] = fmaf(__fdividef(ex - 1.f, ex + 1.f), vv[nt], part[mt][r]);
      }
    }
  }
  float* red = (float*)(lds + RED_OFF);
  #pragma unroll
  for (int mt = 0; mt < 4; ++mt) {
    #pragma unroll
    for (int r = 0; r < 4; ++r) {
      float s = part[mt][r];
      s += __shfl_xor(s, 1);
      s += __shfl_xor(s, 2);
      s += __shfl_xor(s, 4);
      s += __shfl_xor(s, 8);
      if (ln == 0) red[wv * 64 + mt * 16 + q * 4 + r] = s;
    }
  }
  __syncthreads();
  if (tid < 64)
    scores[m0 + tid] = red[tid] + red[64 + tid] + red[128 + tid] + red[192 + tid];
}

// ---------------- K2: softmax over S per b ----------------------------------
__global__ __launch_bounds__(256) void k_softmax(const float* __restrict__ scores,
                                                 float* __restrict__ attn) {
  const int b = blockIdx.x, tid = threadIdx.x;
  float l[8];
  float mx = -3.4e38f;
  #pragma unroll
  for (int i = 0; i < 8; ++i) {
    l[i] = scores[b * S_N + i * 256 + tid];
    mx = fmaxf(mx, l[i]);
  }
  #pragma unroll
  for (int m = 1; m < 64; m <<= 1) mx = fmaxf(mx, __shfl_xor(mx, m));
  __shared__ float sred[8];
  if ((tid & 63) == 0) sred[tid >> 6] = mx;
  __syncthreads();
  mx = fmaxf(fmaxf(sred[0], sred[1]), fmaxf(sred[2], sred[3]));
  float se = 0.f;
  #pragma unroll
  for (int i = 0; i < 8; ++i) { l[i] = __expf(l[i] - mx); se += l[i]; }
  #pragma unroll
  for (int m = 1; m < 64; m <<= 1) se += __shfl_xor(se, m);
  if ((tid & 63) == 0) sred[4 + (tid >> 6)] = se;
  __syncthreads();
  se = sred[4] + sred[5] + sred[6] + sred[7];
  const float inv = 1.f / se;
  #pragma unroll
  for (int i = 0; i < 8; ++i) attn[b * S_N + i * 256 + tid] = l[i] * inv;
}

// ---------------- K3: context[b][e] = sum_s w[b][s] * enc[b][s][e] ----------
__global__ __launch_bounds__(512) void k_context(const float* __restrict__ enc,
                                                 const float* __restrict__ attn,
                                                 float* __restrict__ ctx) {
  const int blk = blockIdx.x;
  const int b = blk >> 2, eq = blk & 3;
  const int tid = threadIdx.x;
  const int te = tid & 31, sg = tid >> 5;   // 16 s-groups of 128 rows
  const int e0 = eq * 128 + te * 4;
  const float* ep = enc + (size_t)b * S_N * E_N + e0;
  const float* wp = attn + b * S_N;
  f32x4 acc = {0.f, 0.f, 0.f, 0.f};
  const int s0 = sg * 128;
  #pragma unroll 4
  for (int s = s0; s < s0 + 128; ++s) {
    const float w = wp[s];
    const f32x4 ev = *(const f32x4*)(ep + (size_t)s * E_N);
    acc += w * ev;
  }
  __shared__ f32x4 red[16][32];
  red[sg][te] = acc;
  __syncthreads();
  if (sg == 0) {
    f32x4 t = red[0][te];
    #pragma unroll
    for (int g = 1; g < 16; ++g) t += red[g][te];
    *(f32x4*)(ctx + (size_t)b * E_N + e0) = t;
  }
}

// ---------------- launch ----------------------------------------------------
extern "C" void kernel_launch(void* const* d_in, const int* in_sizes, int n_in,
                              void* d_out, int out_size, void* d_ws, size_t ws_size,
                              hipStream_t stream) {
  const float* enc = (const float*)d_in[0];
  const float* dh  = (const float*)d_in[1];
  const float* We  = (const float*)d_in[2];
  const float* Wd  = (const float*)d_in[3];
  const float* v   = (const float*)d_in[4];

  float* out_ctx  = (float*)d_out;
  float* out_attn = out_ctx + B_N * E_N;

  float* scores = (float*)d_ws;                       // 131072 f32
  float* decp   = scores + B_N * S_N;                 // 32768 f32
  unsigned short* Wbf = (unsigned short*)(decp + B_N * A_N);  // 262144 bf16

  k_convw  <<<256, 256, 0, stream>>>(We, Wbf);
  k_decproj<<<B_N, 256, 0, stream>>>(dh, Wd, decp);
  k_scores <<<(B_N * S_N) / 64, 256, 0, stream>>>(enc, Wbf, decp, v, scores);
  k_softmax<<<B_N, 256, 0, stream>>>(scores, out_attn);
  k_context<<<B_N * 4, 512, 0, stream>>>(enc, out_attn, out_ctx);
}